// Round 12
// baseline (428.210 us; speedup 1.0000x reference)
//
#include <hip/hip_runtime.h>
#include <hip/hip_bf16.h>

#define D_DIM 128
#define N_ENT 100000
#define R_REL 8
#define E_EDGE 131072
#define B_HEAD 32768
#define NH_PAD 100352  // multiple of 256 >= N_ENT
#define MAXE (R_REL * E_EDGE)

typedef __attribute__((ext_vector_type(8))) short short8v;
typedef __attribute__((ext_vector_type(16))) float f32x16;
typedef unsigned int uint;
typedef unsigned short ushort;

union BF8 {
  short8v v;
  __hip_bfloat16 h[8];
};

__device__ inline ushort bfbits(float x) {
  union { __hip_bfloat16 h; ushort u; } c;
  c.h = __float2bfloat16(x);
  return c.u;
}
__device__ inline float bflo(uint p) { return __uint_as_float(p << 16); }
__device__ inline float bfhi(uint p) { return __uint_as_float(p & 0xffff0000u); }

// ---------- setup: init cnt/inv + prep_W + prep_tail in ONE dispatch ----------
// blocks [0, 3136): init (R*NH_PAD/256)
// blocks [3136, 3208): prep_W (9 mats x 8 blocks)
// blocks [3208, 9458): prep_tail (6250 blocks)
__global__ __launch_bounds__(256) void setup(int* __restrict__ cnt_e,
                                             int* __restrict__ inv,
                                             const float* __restrict__ W,
                                             const float* __restrict__ relW,
                                             short8v* __restrict__ WhS,
                                             const float* __restrict__ tail,
                                             short8v* __restrict__ tailb) {
  int bid = blockIdx.x;
  int tid = threadIdx.x;
  if (bid < 3136) {
    int i = bid * 256 + tid;
    if (i < R_REL * B_HEAD) cnt_e[i] = 0;
    inv[i] = -1;
  } else if (bid < 3208) {
    int b = bid - 3136;
    int mat = b >> 3;
    int idx = (b & 7) * 256 + tid;  // 0..2047
    int o = idx & 127, ks = idx >> 7;
    float v[8];
    if (mat == 0) {
      const float* src = W + o * D_DIM + ks * 8;
#pragma unroll
      for (int j = 0; j < 8; ++j) v[j] = src[j];
    } else {
      const float* src =
          relW + (size_t)(mat - 1) * D_DIM * D_DIM + (ks * 8) * D_DIM + o;
#pragma unroll
      for (int j = 0; j < 8; ++j) v[j] = src[j * D_DIM];
    }
    BF8 h;
#pragma unroll
    for (int j = 0; j < 8; ++j) h.h[j] = __float2bfloat16(v[j]);
    WhS[(size_t)mat * 2048 + idx] = h.v;
  } else {
    int i = (bid - 3208) * 256 + tid;
    const float4* s = (const float4*)tail + (size_t)i * 2;
    float4 a = s[0], b = s[1];
    BF8 h;
    h.h[0] = __float2bfloat16(a.x); h.h[1] = __float2bfloat16(a.y);
    h.h[2] = __float2bfloat16(a.z); h.h[3] = __float2bfloat16(a.w);
    h.h[4] = __float2bfloat16(b.x); h.h[5] = __float2bfloat16(b.y);
    h.h[6] = __float2bfloat16(b.z); h.h[7] = __float2bfloat16(b.w);
    tailb[i] = h.v;
  }
}

// ---------- histogram edges + build head-inverse in one dispatch ----------
__global__ __launch_bounds__(256) void hist_inv(const int* __restrict__ erow,
                                                const int* __restrict__ head,
                                                int* __restrict__ cnt,
                                                int* __restrict__ inv) {
  int bid = blockIdx.x;
  if (bid < 4096) {  // hist: 8 rel x 512 blocks
    int r = bid >> 9;
    int e = (bid & 511) * 256 + threadIdx.x;
    int row = erow[(size_t)r * E_EDGE + e];
    atomicAdd(cnt + r * B_HEAD + row, 1);
  } else {  // build_inv over R*B
    int i = (bid - 4096) * 256 + threadIdx.x;
    int r = i >> 15;
    inv[r * NH_PAD + head[i]] = i & (B_HEAD - 1);
  }
}

// scan phase A: 256 blocks x 1024 elems; cur = block-local exclusive, bsum = totals
__global__ __launch_bounds__(256) void scan_blk(const int* __restrict__ cnt,
                                                int* __restrict__ cur,
                                                int* __restrict__ bsum) {
  int b = blockIdx.x, t = threadIdx.x;
  int4 v = ((const int4*)cnt)[b * 256 + t];
  int s = v.x + v.y + v.z + v.w;
  __shared__ int ps[256];
  ps[t] = s;
  __syncthreads();
  for (int off = 1; off < 256; off <<= 1) {
    int u = (t >= off) ? ps[t - off] : 0;
    __syncthreads();
    ps[t] += u;
    __syncthreads();
  }
  int base = ps[t] - s;
  int4 o;
  o.x = base; o.y = base + v.x; o.z = o.y + v.y; o.w = o.z + v.z;
  ((int4*)cur)[b * 256 + t] = o;
  if (t == 255) bsum[b] = ps[255];
}

// scan phase B: exclusive scan of 256 block sums (bsum base added at USE sites)
__global__ __launch_bounds__(256) void scan_bsum(int* __restrict__ bsum) {
  int t = threadIdx.x;
  int s = bsum[t];
  __shared__ int ps[256];
  ps[t] = s;
  __syncthreads();
  for (int off = 1; off < 256; off <<= 1) {
    int u = (t >= off) ? ps[t - off] : 0;
    __syncthreads();
    ps[t] += u;
    __syncthreads();
  }
  bsum[t] = ps[t] - s;
}

// scatter with bsum fold: pos = local atomic cursor + block base
__global__ __launch_bounds__(256) void scatter_edges(const int* __restrict__ erow,
                                                     const int* __restrict__ ecol,
                                                     const float* __restrict__ ew,
                                                     int* __restrict__ cur,
                                                     const int* __restrict__ bsum,
                                                     int2* __restrict__ sColW) {
  int r = blockIdx.y;
  int e = blockIdx.x * 256 + threadIdx.x;
  size_t idx = (size_t)r * E_EDGE + e;
  int row = erow[idx];
  int gi = r * B_HEAD + row;
  int pos = atomicAdd(cur + gi, 1) + bsum[gi >> 10];
  sColW[pos] = make_int2(ecol[idx], __float_as_int(ew[idx]));
}

// ---------- FUSED: csr_agg (gather, no LDS) || x-GEMM (no LDS, B from L2) ----------
// Every P-th block is an x-gemm block (nxb total); the rest are csr blocks.
__global__ __launch_bounds__(256) void fused_csr_xgemm(
    const uint* __restrict__ tailb, const float* __restrict__ x,
    const short8v* __restrict__ WhS, const int* __restrict__ cur_e,
    const int* __restrict__ cnt_e, const int* __restrict__ bsum,
    const int2* __restrict__ sColW, uint* __restrict__ aggb,
    float* __restrict__ out, int r0, int nxb, int P, int csrB) {
  int bid = blockIdx.x;
  int tid = threadIdx.x;
  bool isg = (nxb > 0) && (bid % P == 0) && (bid / P < nxb);

  if (isg) {
    // ---- x-GEMM block: rows [gid*128, +128) of x @ W^T -> out (f32) ----
    // B fragments straight from global (36 KB image, L2-resident, 782 readers).
    int gid = bid / P;
    int w = tid >> 6, lane = tid & 63, lrow = lane & 31, lsel = lane >> 5;
    int rowbase = gid * 128;
    int arow = rowbase + w * 32 + lrow;
    int arowc = (arow < N_ENT) ? arow : (N_ENT - 1);
    const float4* Arow = (const float4*)(x + (size_t)arowc * D_DIM);
    f32x16 acc[4] = {};
#pragma unroll
    for (int kk = 0; kk < 8; ++kk) {
      int ks = kk * 2 + lsel;
      short8v b0 = WhS[ks * 128 + 0 * 32 + lrow];
      short8v b1 = WhS[ks * 128 + 1 * 32 + lrow];
      short8v b2 = WhS[ks * 128 + 2 * 32 + lrow];
      short8v b3 = WhS[ks * 128 + 3 * 32 + lrow];
      float4 a0 = Arow[kk * 4 + lsel * 2];
      float4 a1 = Arow[kk * 4 + lsel * 2 + 1];
      BF8 ah;
      ah.h[0] = __float2bfloat16(a0.x); ah.h[1] = __float2bfloat16(a0.y);
      ah.h[2] = __float2bfloat16(a0.z); ah.h[3] = __float2bfloat16(a0.w);
      ah.h[4] = __float2bfloat16(a1.x); ah.h[5] = __float2bfloat16(a1.y);
      ah.h[6] = __float2bfloat16(a1.z); ah.h[7] = __float2bfloat16(a1.w);
      acc[0] = __builtin_amdgcn_mfma_f32_32x32x16_bf16(ah.v, b0, acc[0], 0, 0, 0);
      acc[1] = __builtin_amdgcn_mfma_f32_32x32x16_bf16(ah.v, b1, acc[1], 0, 0, 0);
      acc[2] = __builtin_amdgcn_mfma_f32_32x32x16_bf16(ah.v, b2, acc[2], 0, 0, 0);
      acc[3] = __builtin_amdgcn_mfma_f32_32x32x16_bf16(ah.v, b3, acc[3], 0, 0, 0);
    }
    int wrow0 = rowbase + w * 32;
#pragma unroll
    for (int reg = 0; reg < 16; ++reg) {
      int srow = wrow0 + (reg & 3) + 8 * (reg >> 2) + 4 * lsel;
      if (srow < N_ENT) {
        float* orow = out + (size_t)srow * D_DIM;
#pragma unroll
        for (int n = 0; n < 4; ++n) orow[n * 32 + lrow] = acc[n][reg];
      }
    }
    return;
  }

  // ---- csr block: 8 rows, 2 per wave, 8-edge batched loads ----
  int cid = (nxb > 0) ? (bid - bid / P - 1) : bid;
  if (cid >= csrB) return;
  int base = (cid << 3) + ((tid >> 6) << 1);
  int lane = tid & 63;
  int li = lane & 7;
  int f0 = r0 * B_HEAD + base, f1 = f0 + 1;
  int cn0 = cnt_e[f0], cn1 = cnt_e[f1];
  int s0 = cur_e[f0] - cn0 + bsum[f0 >> 10];
  int s1 = cur_e[f1] - cn1 + bsum[f1 >> 10];
  float a0x = 0.f, a0y = 0.f, a1x = 0.f, a1y = 0.f;
  int rounds = ((cn0 > cn1 ? cn0 : cn1) + 7) >> 3;
  for (int rr = 0; rr < rounds; ++rr) {
    int k = rr << 3;
    int i0 = k + li; if (i0 > cn0 - 1) i0 = cn0 > 0 ? cn0 - 1 : 0;
    int i1 = k + li; if (i1 > cn1 - 1) i1 = cn1 > 0 ? cn1 - 1 : 0;
    int g0 = s0 + i0; if (g0 > MAXE - 1) g0 = MAXE - 1;
    int g1 = s1 + i1; if (g1 > MAXE - 1) g1 = MAXE - 1;
    int2 ea = sColW[g0];
    int2 eb = sColW[g1];
#pragma unroll
    for (int j = 0; j < 8; ++j) {
      if (k + j < cn0) {  // wave-uniform
        int col = __shfl(ea.x, j, 8);
        float w = __int_as_float(__shfl(ea.y, j, 8));
        uint t = tailb[(size_t)col * 64 + lane];
        a0x += w * bflo(t); a0y += w * bfhi(t);
      }
      if (k + j < cn1) {  // wave-uniform
        int col = __shfl(eb.x, j, 8);
        float w = __int_as_float(__shfl(eb.y, j, 8));
        uint t = tailb[(size_t)col * 64 + lane];
        a1x += w * bflo(t); a1y += w * bfhi(t);
      }
    }
  }
  aggb[(size_t)base * 64 + lane] = (uint)bfbits(a0x) | ((uint)bfbits(a0y) << 16);
  aggb[(size_t)(base + 1) * 64 + lane] = (uint)bfbits(a1x) | ((uint)bfbits(a1y) << 16);
}

// ---------- rel GEMM (LDS-staged single-bf16 B): aggb @ relW -> updb ----------
__global__ __launch_bounds__(256) void gemm_rel(const ushort* __restrict__ aggb,
                                                const short8v* __restrict__ WhS,
                                                ushort* __restrict__ updb, int r0) {
  __shared__ short8v wlds[16][128];  // 32 KB
  int tid = threadIdx.x;
  int relloc = blockIdx.y;
  int mat = 1 + r0 + relloc;
  const short8v* Bsrc = WhS + (size_t)mat * 2048;
#pragma unroll
  for (int it = 0; it < 8; ++it) {
    int e = it * 256 + tid;
    wlds[e >> 7][e & 127] = Bsrc[e];
  }
  int w = tid >> 6, lane = tid & 63, lrow = lane & 31, lsel = lane >> 5;
  int rowbase = blockIdx.x * 128;
  int arow = rowbase + w * 32 + lrow;
  const short8v* Arow =
      (const short8v*)(aggb + ((size_t)relloc * B_HEAD + arow) * D_DIM);
  f32x16 acc[4] = {};
  __syncthreads();
#pragma unroll
  for (int kk = 0; kk < 8; ++kk) {
    short8v a = Arow[kk * 2 + lsel];
    int ks = kk * 2 + lsel;
#pragma unroll
    for (int n = 0; n < 4; ++n)
      acc[n] = __builtin_amdgcn_mfma_f32_32x32x16_bf16(a, wlds[ks][n * 32 + lrow],
                                                       acc[n], 0, 0, 0);
  }
  int wrow0 = rowbase + w * 32;
  ushort* ubase = updb + (size_t)relloc * B_HEAD * D_DIM;
#pragma unroll
  for (int reg = 0; reg < 16; ++reg) {
    int srow = wrow0 + (reg & 3) + 8 * (reg >> 2) + 4 * lsel;
    ushort* urow = ubase + (size_t)srow * D_DIM;
#pragma unroll
    for (int n = 0; n < 4; ++n) urow[n * 32 + lrow] = bfbits(acc[n][reg]);
  }
}

// out[n] += upd rows (bf16) of relations [r0, r0+c); optional relu.
__global__ __launch_bounds__(256) void final_add(const int* __restrict__ inv,
                                                 const ushort* __restrict__ updb,
                                                 float* __restrict__ out, int r0,
                                                 int c, int doRelu) {
  int n = blockIdx.x * 8 + (threadIdx.x >> 5);
  int lane = threadIdx.x & 31;
  if (n >= N_ENT) return;
  float4* o4 = (float4*)out + (size_t)n * 32 + lane;
  float4 v = *o4;
  for (int k = 0; k < c; ++k) {
    int row = inv[(r0 + k) * NH_PAD + n];
    if (row >= 0) {
      uint2 u = ((const uint2*)updb)[((size_t)k * B_HEAD + row) * 32 + lane];
      v.x += bflo(u.x); v.y += bfhi(u.x);
      v.z += bflo(u.y); v.w += bfhi(u.y);
    }
  }
  if (doRelu) {
    v.x = fmaxf(v.x, 0.f); v.y = fmaxf(v.y, 0.f);
    v.z = fmaxf(v.z, 0.f); v.w = fmaxf(v.w, 0.f);
  }
  *o4 = v;
}

extern "C" void kernel_launch(void* const* d_in, const int* in_sizes, int n_in,
                              void* d_out, int out_size, void* d_ws, size_t ws_size,
                              hipStream_t stream) {
  const float* x = (const float*)d_in[0];
  const float* tail = (const float*)d_in[1];
  const float* W = (const float*)d_in[2];
  const float* relW = (const float*)d_in[3];
  const float* ew = (const float*)d_in[4];
  const int* erow = (const int*)d_in[5];
  const int* ecol = (const int*)d_in[6];
  const int* head = (const int*)d_in[7];
  float* out = (float*)d_out;

  // ws layout (16B-aligned chunks):
  char* p = (char*)d_ws;
  short8v* WhS = (short8v*)p;   p += (size_t)(R_REL + 1) * 2048 * 16;
  short8v* tailb = (short8v*)p; p += (size_t)N_ENT * D_DIM * 2;
  int* cnt_e = (int*)p;         p += (size_t)R_REL * B_HEAD * 4;
  int* cur_e = (int*)p;         p += (size_t)R_REL * B_HEAD * 4;
  int* inv = (int*)p;           p += (size_t)R_REL * NH_PAD * 4;
  int* bsum = (int*)p;          p += 256 * 4;
  int2* sColW = (int2*)p;       p += (size_t)R_REL * E_EDGE * 8;
  char* dyn = p;  // aggb (chunk*B*128*2) + updb (chunk*B*128*2)
  size_t fixed = (size_t)(p - (char*)d_ws);
  size_t per_rel = (size_t)B_HEAD * D_DIM * 2 * 2;  // aggb + updb, bf16
  size_t avail = (ws_size > fixed) ? ws_size - fixed : 0;
  int chunk = (int)(avail / per_rel);
  if (chunk > R_REL) chunk = R_REL;
  if (chunk < 1) chunk = 1;
  ushort* aggb = (ushort*)dyn;
  ushort* updb = (ushort*)(dyn + (size_t)chunk * B_HEAD * D_DIM * 2);

  const int NXB = (N_ENT + 127) / 128;  // 782

  setup<<<dim3(3136 + 72 + 6250), 256, 0, stream>>>(cnt_e, inv, W, relW, WhS, tail,
                                                    tailb);
  hist_inv<<<dim3(4096 + R_REL * B_HEAD / 256), 256, 0, stream>>>(erow, head, cnt_e,
                                                                  inv);
  scan_blk<<<dim3(256), 256, 0, stream>>>(cnt_e, cur_e, bsum);
  scan_bsum<<<dim3(1), 256, 0, stream>>>(bsum);
  scatter_edges<<<dim3(E_EDGE / 256, R_REL), 256, 0, stream>>>(erow, ecol, ew, cur_e,
                                                               bsum, sColW);

  for (int r0 = 0; r0 < R_REL; r0 += chunk) {
    int c = (R_REL - r0 < chunk) ? (R_REL - r0) : chunk;
    int csrB = c * B_HEAD / 8;
    int nxb = (r0 == 0) ? NXB : 0;  // x-GEMM rides the first chunk's dispatch
    int P = 1, grid = csrB;
    if (nxb > 0) {
      P = (csrB + nxb - 1) / nxb + 1;
      grid = nxb * P;
    }
    fused_csr_xgemm<<<dim3(grid), 256, 0, stream>>>(
        (const uint*)tailb, x, WhS, cur_e, cnt_e, bsum, sColW, (uint*)aggb, out, r0,
        nxb, P, csrB);
    gemm_rel<<<dim3(B_HEAD / 128, c), 256, 0, stream>>>(aggb, WhS, updb, r0);
    final_add<<<dim3((N_ENT + 7) / 8), 256, 0, stream>>>(inv, updb, out, r0, c,
                                                         (r0 + c == R_REL) ? 1 : 0);
  }
}

// Round 13
// 310.808 us; speedup vs baseline: 1.3777x; 1.3777x over previous
//
#include <hip/hip_runtime.h>
#include <hip/hip_bf16.h>

#define D_DIM 128
#define N_ENT 100000
#define R_REL 8
#define E_EDGE 131072
#define B_HEAD 32768
#define NH_PAD 100352  // multiple of 256 >= N_ENT
#define MAXE (R_REL * E_EDGE)

typedef __attribute__((ext_vector_type(8))) short short8v;
typedef __attribute__((ext_vector_type(16))) float f32x16;
typedef unsigned int uint;
typedef unsigned short ushort;

union BF8 {
  short8v v;
  __hip_bfloat16 h[8];
};

__device__ inline ushort bfbits(float x) {
  union { __hip_bfloat16 h; ushort u; } c;
  c.h = __float2bfloat16(x);
  return c.u;
}
__device__ inline float bflo(uint p) { return __uint_as_float(p << 16); }
__device__ inline float bfhi(uint p) { return __uint_as_float(p & 0xffff0000u); }

// ---------- setup: init cnt/inv + prep_W + prep_tail in ONE dispatch ----------
// blocks [0, 3136): init (R*NH_PAD/256)
// blocks [3136, 3208): prep_W (9 mats x 8 blocks)
// blocks [3208, 9458): prep_tail (6250 blocks)
__global__ __launch_bounds__(256) void setup(int* __restrict__ cnt_e,
                                             int* __restrict__ inv,
                                             const float* __restrict__ W,
                                             const float* __restrict__ relW,
                                             short8v* __restrict__ WhS,
                                             const float* __restrict__ tail,
                                             short8v* __restrict__ tailb) {
  int bid = blockIdx.x;
  int tid = threadIdx.x;
  if (bid < 3136) {
    int i = bid * 256 + tid;
    if (i < R_REL * B_HEAD) cnt_e[i] = 0;
    inv[i] = -1;
  } else if (bid < 3208) {
    int b = bid - 3136;
    int mat = b >> 3;
    int idx = (b & 7) * 256 + tid;  // 0..2047
    int o = idx & 127, ks = idx >> 7;
    float v[8];
    if (mat == 0) {
      const float* src = W + o * D_DIM + ks * 8;
#pragma unroll
      for (int j = 0; j < 8; ++j) v[j] = src[j];
    } else {
      const float* src =
          relW + (size_t)(mat - 1) * D_DIM * D_DIM + (ks * 8) * D_DIM + o;
#pragma unroll
      for (int j = 0; j < 8; ++j) v[j] = src[j * D_DIM];
    }
    BF8 h;
#pragma unroll
    for (int j = 0; j < 8; ++j) h.h[j] = __float2bfloat16(v[j]);
    WhS[(size_t)mat * 2048 + idx] = h.v;
  } else {
    int i = (bid - 3208) * 256 + tid;
    const float4* s = (const float4*)tail + (size_t)i * 2;
    float4 a = s[0], b = s[1];
    BF8 h;
    h.h[0] = __float2bfloat16(a.x); h.h[1] = __float2bfloat16(a.y);
    h.h[2] = __float2bfloat16(a.z); h.h[3] = __float2bfloat16(a.w);
    h.h[4] = __float2bfloat16(b.x); h.h[5] = __float2bfloat16(b.y);
    h.h[6] = __float2bfloat16(b.z); h.h[7] = __float2bfloat16(b.w);
    tailb[i] = h.v;
  }
}

// ---------- histogram edges + build head-inverse in one dispatch ----------
__global__ __launch_bounds__(256) void hist_inv(const int* __restrict__ erow,
                                                const int* __restrict__ head,
                                                int* __restrict__ cnt,
                                                int* __restrict__ inv) {
  int bid = blockIdx.x;
  if (bid < 4096) {  // hist: 8 rel x 512 blocks
    int r = bid >> 9;
    int e = (bid & 511) * 256 + threadIdx.x;
    int row = erow[(size_t)r * E_EDGE + e];
    atomicAdd(cnt + r * B_HEAD + row, 1);
  } else {  // build_inv over R*B
    int i = (bid - 4096) * 256 + threadIdx.x;
    int r = i >> 15;
    inv[r * NH_PAD + head[i]] = i & (B_HEAD - 1);
  }
}

// scan phase A: 256 blocks x 1024 elems; cur = block-local exclusive, bsum = totals
__global__ __launch_bounds__(256) void scan_blk(const int* __restrict__ cnt,
                                                int* __restrict__ cur,
                                                int* __restrict__ bsum) {
  int b = blockIdx.x, t = threadIdx.x;
  int4 v = ((const int4*)cnt)[b * 256 + t];
  int s = v.x + v.y + v.z + v.w;
  __shared__ int ps[256];
  ps[t] = s;
  __syncthreads();
  for (int off = 1; off < 256; off <<= 1) {
    int u = (t >= off) ? ps[t - off] : 0;
    __syncthreads();
    ps[t] += u;
    __syncthreads();
  }
  int base = ps[t] - s;
  int4 o;
  o.x = base; o.y = base + v.x; o.z = o.y + v.y; o.w = o.z + v.z;
  ((int4*)cur)[b * 256 + t] = o;
  if (t == 255) bsum[b] = ps[255];
}

// scan phase B: exclusive scan of 256 block sums (bsum base added at USE sites)
__global__ __launch_bounds__(256) void scan_bsum(int* __restrict__ bsum) {
  int t = threadIdx.x;
  int s = bsum[t];
  __shared__ int ps[256];
  ps[t] = s;
  __syncthreads();
  for (int off = 1; off < 256; off <<= 1) {
    int u = (t >= off) ? ps[t - off] : 0;
    __syncthreads();
    ps[t] += u;
    __syncthreads();
  }
  bsum[t] = ps[t] - s;
}

// scatter with bsum fold: pos = local atomic cursor + block base
__global__ __launch_bounds__(256) void scatter_edges(const int* __restrict__ erow,
                                                     const int* __restrict__ ecol,
                                                     const float* __restrict__ ew,
                                                     int* __restrict__ cur,
                                                     const int* __restrict__ bsum,
                                                     int2* __restrict__ sColW) {
  int r = blockIdx.y;
  int e = blockIdx.x * 256 + threadIdx.x;
  size_t idx = (size_t)r * E_EDGE + e;
  int row = erow[idx];
  int gi = r * B_HEAD + row;
  int pos = atomicAdd(cur + gi, 1) + bsum[gi >> 10];
  sColW[pos] = make_int2(ecol[idx], __float_as_int(ew[idx]));
}

// ---------- aggregation: 2 rows per wave, 8-edge batched loads ----------
__global__ __launch_bounds__(256) void csr_agg(const uint* __restrict__ tailb,
                                               const int* __restrict__ cur_e,
                                               const int* __restrict__ cnt_e,
                                               const int* __restrict__ bsum,
                                               const int2* __restrict__ sColW,
                                               uint* __restrict__ aggb, int r0) {
  int base = (blockIdx.x << 3) + ((threadIdx.x >> 6) << 1);  // 8 rows/block, 2/wave
  int lane = threadIdx.x & 63;
  int li = lane & 7;
  int f0 = r0 * B_HEAD + base, f1 = f0 + 1;
  int cn0 = cnt_e[f0], cn1 = cnt_e[f1];
  int s0 = cur_e[f0] - cn0 + bsum[f0 >> 10];
  int s1 = cur_e[f1] - cn1 + bsum[f1 >> 10];
  float a0x = 0.f, a0y = 0.f, a1x = 0.f, a1y = 0.f;
  int rounds = ((cn0 > cn1 ? cn0 : cn1) + 7) >> 3;
  for (int rr = 0; rr < rounds; ++rr) {
    int k = rr << 3;
    int i0 = k + li; if (i0 > cn0 - 1) i0 = cn0 > 0 ? cn0 - 1 : 0;
    int i1 = k + li; if (i1 > cn1 - 1) i1 = cn1 > 0 ? cn1 - 1 : 0;
    int g0 = s0 + i0; if (g0 > MAXE - 1) g0 = MAXE - 1;
    int g1 = s1 + i1; if (g1 > MAXE - 1) g1 = MAXE - 1;
    int2 ea = sColW[g0];
    int2 eb = sColW[g1];
#pragma unroll
    for (int j = 0; j < 8; ++j) {
      if (k + j < cn0) {  // wave-uniform
        int col = __shfl(ea.x, j, 8);
        float w = __int_as_float(__shfl(ea.y, j, 8));
        uint t = tailb[(size_t)col * 64 + lane];
        a0x += w * bflo(t); a0y += w * bfhi(t);
      }
      if (k + j < cn1) {  // wave-uniform
        int col = __shfl(eb.x, j, 8);
        float w = __int_as_float(__shfl(eb.y, j, 8));
        uint t = tailb[(size_t)col * 64 + lane];
        a1x += w * bflo(t); a1y += w * bfhi(t);
      }
    }
  }
  aggb[(size_t)base * 64 + lane] = (uint)bfbits(a0x) | ((uint)bfbits(a0y) << 16);
  aggb[(size_t)(base + 1) * 64 + lane] = (uint)bfbits(a1x) | ((uint)bfbits(a1y) << 16);
}

// ---------- unified GEMM (single-bf16 B, one MFMA per k-step): ----------
// blocks [0,nxb): x (f32, in-register cvt) @ W^T -> out (f32)
// blocks [nxb, nxb+256*c): aggb (bf16) @ relW -> updb (bf16)
__global__ __launch_bounds__(256) void gemm_all(const float* __restrict__ x,
                                                const ushort* __restrict__ aggb,
                                                const short8v* __restrict__ WhS,
                                                float* __restrict__ out,
                                                ushort* __restrict__ updb, int r0,
                                                int nxb) {
  __shared__ short8v wlds[16][128];  // 32 KB, full B image
  int tid = threadIdx.x;
  int bid = blockIdx.x;
  bool xpart = (bid < nxb);
  int mat, rowbase, relloc = 0;
  if (xpart) {
    mat = 0;
    rowbase = bid * 128;
  } else {
    int b = bid - nxb;
    relloc = b >> 8;
    mat = 1 + r0 + relloc;
    rowbase = (b & 255) * 128;
  }
  const short8v* Bsrc = WhS + (size_t)mat * 2048;
#pragma unroll
  for (int it = 0; it < 8; ++it) {
    int e = it * 256 + tid;
    wlds[e >> 7][e & 127] = Bsrc[e];
  }
  int w = tid >> 6, lane = tid & 63, lrow = lane & 31, lsel = lane >> 5;
  int arow = rowbase + w * 32 + lrow;
  f32x16 acc[4] = {};
  __syncthreads();

  if (xpart) {
    int arowc = (arow < N_ENT) ? arow : (N_ENT - 1);
    const float4* Arow = (const float4*)(x + (size_t)arowc * D_DIM);
#pragma unroll
    for (int kk = 0; kk < 8; ++kk) {
      float4 a0 = Arow[kk * 4 + lsel * 2];
      float4 a1 = Arow[kk * 4 + lsel * 2 + 1];
      BF8 ah;
      ah.h[0] = __float2bfloat16(a0.x); ah.h[1] = __float2bfloat16(a0.y);
      ah.h[2] = __float2bfloat16(a0.z); ah.h[3] = __float2bfloat16(a0.w);
      ah.h[4] = __float2bfloat16(a1.x); ah.h[5] = __float2bfloat16(a1.y);
      ah.h[6] = __float2bfloat16(a1.z); ah.h[7] = __float2bfloat16(a1.w);
      int ks = kk * 2 + lsel;
#pragma unroll
      for (int n = 0; n < 4; ++n)
        acc[n] = __builtin_amdgcn_mfma_f32_32x32x16_bf16(ah.v, wlds[ks][n * 32 + lrow],
                                                         acc[n], 0, 0, 0);
    }
    int wrow0 = rowbase + w * 32;
#pragma unroll
    for (int reg = 0; reg < 16; ++reg) {
      int srow = wrow0 + (reg & 3) + 8 * (reg >> 2) + 4 * lsel;
      if (srow < N_ENT) {
        float* orow = out + (size_t)srow * D_DIM;
#pragma unroll
        for (int n = 0; n < 4; ++n) orow[n * 32 + lrow] = acc[n][reg];
      }
    }
  } else {
    const short8v* Arow =
        (const short8v*)(aggb + ((size_t)relloc * B_HEAD + arow) * D_DIM);
#pragma unroll
    for (int kk = 0; kk < 8; ++kk) {
      short8v a = Arow[kk * 2 + lsel];
      int ks = kk * 2 + lsel;
#pragma unroll
      for (int n = 0; n < 4; ++n)
        acc[n] = __builtin_amdgcn_mfma_f32_32x32x16_bf16(a, wlds[ks][n * 32 + lrow],
                                                         acc[n], 0, 0, 0);
    }
    int wrow0 = rowbase + w * 32;
    ushort* ubase = updb + (size_t)relloc * B_HEAD * D_DIM;
#pragma unroll
    for (int reg = 0; reg < 16; ++reg) {
      int srow = wrow0 + (reg & 3) + 8 * (reg >> 2) + 4 * lsel;
      ushort* urow = ubase + (size_t)srow * D_DIM;
#pragma unroll
      for (int n = 0; n < 4; ++n) urow[n * 32 + lrow] = bfbits(acc[n][reg]);
    }
  }
}

// out[n] += upd rows (bf16) of relations [r0, r0+c); optional relu.
__global__ __launch_bounds__(256) void final_add(const int* __restrict__ inv,
                                                 const ushort* __restrict__ updb,
                                                 float* __restrict__ out, int r0,
                                                 int c, int doRelu) {
  int n = blockIdx.x * 8 + (threadIdx.x >> 5);
  int lane = threadIdx.x & 31;
  if (n >= N_ENT) return;
  float4* o4 = (float4*)out + (size_t)n * 32 + lane;
  float4 v = *o4;
  for (int k = 0; k < c; ++k) {
    int row = inv[(r0 + k) * NH_PAD + n];
    if (row >= 0) {
      uint2 u = ((const uint2*)updb)[((size_t)k * B_HEAD + row) * 32 + lane];
      v.x += bflo(u.x); v.y += bfhi(u.x);
      v.z += bflo(u.y); v.w += bfhi(u.y);
    }
  }
  if (doRelu) {
    v.x = fmaxf(v.x, 0.f); v.y = fmaxf(v.y, 0.f);
    v.z = fmaxf(v.z, 0.f); v.w = fmaxf(v.w, 0.f);
  }
  *o4 = v;
}

extern "C" void kernel_launch(void* const* d_in, const int* in_sizes, int n_in,
                              void* d_out, int out_size, void* d_ws, size_t ws_size,
                              hipStream_t stream) {
  const float* x = (const float*)d_in[0];
  const float* tail = (const float*)d_in[1];
  const float* W = (const float*)d_in[2];
  const float* relW = (const float*)d_in[3];
  const float* ew = (const float*)d_in[4];
  const int* erow = (const int*)d_in[5];
  const int* ecol = (const int*)d_in[6];
  const int* head = (const int*)d_in[7];
  float* out = (float*)d_out;

  // ws layout (16B-aligned chunks):
  char* p = (char*)d_ws;
  short8v* WhS = (short8v*)p;   p += (size_t)(R_REL + 1) * 2048 * 16;
  short8v* tailb = (short8v*)p; p += (size_t)N_ENT * D_DIM * 2;
  int* cnt_e = (int*)p;         p += (size_t)R_REL * B_HEAD * 4;
  int* cur_e = (int*)p;         p += (size_t)R_REL * B_HEAD * 4;
  int* inv = (int*)p;           p += (size_t)R_REL * NH_PAD * 4;
  int* bsum = (int*)p;          p += 256 * 4;
  int2* sColW = (int2*)p;       p += (size_t)R_REL * E_EDGE * 8;
  char* dyn = p;  // aggb (chunk*B*128*2) + updb (chunk*B*128*2)
  size_t fixed = (size_t)(p - (char*)d_ws);
  size_t per_rel = (size_t)B_HEAD * D_DIM * 2 * 2;  // aggb + updb, bf16
  size_t avail = (ws_size > fixed) ? ws_size - fixed : 0;
  int chunk = (int)(avail / per_rel);
  if (chunk > R_REL) chunk = R_REL;
  if (chunk < 1) chunk = 1;
  ushort* aggb = (ushort*)dyn;
  ushort* updb = (ushort*)(dyn + (size_t)chunk * B_HEAD * D_DIM * 2);

  const int NXB = (N_ENT + 127) / 128;  // 782

  setup<<<dim3(3136 + 72 + 6250), 256, 0, stream>>>(cnt_e, inv, W, relW, WhS, tail,
                                                    tailb);
  hist_inv<<<dim3(4096 + R_REL * B_HEAD / 256), 256, 0, stream>>>(erow, head, cnt_e,
                                                                  inv);
  scan_blk<<<dim3(256), 256, 0, stream>>>(cnt_e, cur_e, bsum);
  scan_bsum<<<dim3(1), 256, 0, stream>>>(bsum);
  scatter_edges<<<dim3(E_EDGE / 256, R_REL), 256, 0, stream>>>(erow, ecol, ew, cur_e,
                                                               bsum, sColW);

  for (int r0 = 0; r0 < R_REL; r0 += chunk) {
    int c = (R_REL - r0 < chunk) ? (R_REL - r0) : chunk;
    csr_agg<<<dim3(c * B_HEAD / 8), 256, 0, stream>>>(
        (const uint*)tailb, cur_e, cnt_e, bsum, sColW, (uint*)aggb, r0);
    int nxb = (r0 == 0) ? NXB : 0;  // x-GEMM rides the first chunk's dispatch
    gemm_all<<<dim3(nxb + 256 * c), 256, 0, stream>>>(x, aggb, WhS, out, updb, r0,
                                                      nxb);
    final_add<<<dim3((N_ENT + 7) / 8), 256, 0, stream>>>(inv, updb, out, r0, c,
                                                         (r0 + c == R_REL) ? 1 : 0);
  }
}